// Round 9
// baseline (458.046 us; speedup 1.0000x reference)
//
#include <hip/hip_runtime.h>
#include <hip/hip_bf16.h>
#include <hip/hip_fp16.h>
#include <cstdint>

// ---------------------------------------------------------------------------
// SPDE GCN: 4x GCNConv + linear head, fp32 in/out.
// R3-R13: uint2 multi-edge MLP agg; fp16 feature table; atomic-free MSD
//   bucket-sort CSR fused with layer-1 GEMM; maskless x8-padded CSR with
//   sentinel row; MFMA fp16 GEMM; head fused; persistent agg with rpc(int4)
//   dist-2 / col dist-1 prefetch.
// R14-R19 forensics: steady aggs ~46us / FETCH 104MB (8 XCD x 12.8MB table =
//   compulsory streaming, random graph) in EVERY config; totals carry
//   +-15-30us container noise -> trust per-dispatch counters only.
//   MFMA gemm1 real win; x8 padding + R13 agg pipeline are the optimum.
// R20: dense 32ch layer-4 table (halves final-agg streaming).  352.0us.
// R21 (this round): FUSE next-layer GEMM into agg.  Chunked mapping
//   (16 nodes/wave); gather phase unchanged per node; h rows staged in
//   per-wave LDS tile (stride 72 = 2-way banks); then 2xNT MFMAs in-wave
//   (same fragment path as gemm_mfma_k), x dinv, write next table directly.
//   Ping-pong T1/T2.  Eliminates 3 gemm dispatches + H round-trip (-77MB);
//   MFMA work rides agg's idle VALU/latency shadow.  Bit-exact math path.
// ---------------------------------------------------------------------------

#define MAXD 512       // max coarse digits (n <= 131072)
#define EB   8192      // edges per hist/pack chunk
#define PADSLACK 2048  // max per-bucket padding (256 nodes * 8)

typedef _Float16 half8v __attribute__((ext_vector_type(8)));
typedef _Float16 half2v __attribute__((ext_vector_type(2)));
typedef float    float4v __attribute__((ext_vector_type(4)));

#if defined(__has_builtin)
#if __has_builtin(__builtin_amdgcn_fdot2)
#define HAVE_FDOT2 1
#endif
#endif

__device__ __forceinline__ float fdot2f(half2v a, half2v b, float c) {
#ifdef HAVE_FDOT2
    return __builtin_amdgcn_fdot2(a, b, c, false);
#else
    return c + (float)a[0] * (float)b[0] + (float)a[1] * (float)b[1];
#endif
}

// ---- LDS exclusive scan of totals[0..MAXD) with 256 threads ---------------
__device__ __forceinline__ void digit_base_scan(const int* __restrict__ totals,
                                                int ND, int* pairs, int* cbs) {
    const int t = threadIdx.x;
    const int e0 = 2 * t, e1 = 2 * t + 1;
    int v0 = (e0 < ND) ? totals[e0] : 0;
    int v1 = (e1 < ND) ? totals[e1] : 0;
    pairs[t] = v0 + v1;
    __syncthreads();
    for (int off = 1; off < 256; off <<= 1) {
        int x = (t >= off) ? pairs[t - off] : 0;
        __syncthreads();
        pairs[t] += x;
        __syncthreads();
    }
    int ep = pairs[t] - v0 - v1;  // exclusive pair prefix
    cbs[e0] = ep;
    cbs[e1] = ep + v0;
    __syncthreads();
}

// ---- hist body: coarse histogram (block-major histM[b][dg]) ---------------
__device__ __forceinline__ void hist_body(const int* __restrict__ ei,
                                          int* __restrict__ histM, int E, int b) {
    __shared__ int hist[MAXD];
    const int tid = threadIdx.x;
    hist[tid] = 0; hist[tid + 256] = 0;
    __syncthreads();
    const int base = b * EB;
#pragma unroll 2
    for (int it = 0; it < EB / 256; it += 4) {
        int d[4]; bool ok[4];
#pragma unroll
        for (int u = 0; u < 4; ++u) {
            int e = base + (it + u) * 256 + tid;
            ok[u] = e < E;
            d[u] = ok[u] ? ei[E + e] : 0;
        }
#pragma unroll
        for (int u = 0; u < 4; ++u)
            if (ok[u]) atomicAdd(&hist[d[u] >> 8], 1);
    }
    __syncthreads();
    histM[(size_t)b * MAXD + tid] = hist[tid];
    histM[(size_t)b * MAXD + tid + 256] = hist[tid + 256];
}

// ---- per-digit exclusive scan over chunks (in place) + digit totals -------
__global__ __launch_bounds__(256) void scan_digits_k(int* __restrict__ histM,
                                                     int* __restrict__ totals,
                                                     int NBLK) {
    __shared__ int s[256];
    const int t = threadIdx.x, dg = blockIdx.x;
    int v = (t < NBLK) ? histM[(size_t)t * MAXD + dg] : 0;
    s[t] = v;
    __syncthreads();
    for (int off = 1; off < 256; off <<= 1) {
        int x = (t >= off) ? s[t - off] : 0;
        __syncthreads();
        s[t] += x;
        __syncthreads();
    }
    if (t < NBLK) histM[(size_t)t * MAXD + dg] = s[t] - v;
    if (t == 255) totals[dg] = s[255];
}

// ---- MFMA layer-1 GEMM body: A1[r] = fp16(x[r](fp16) @ W1(fp16)) ----------
__device__ __forceinline__ void gemm1_mfma_body(const float* __restrict__ X,
                                                const float* __restrict__ W,
                                                __half* __restrict__ Aout,
                                                int n, int bx) {
    __shared__ _Float16 WT[64][136];   // W transposed [out][k], +8 pad
    const int t = threadIdx.x;
#pragma unroll
    for (int p = 0; p < 8; ++p) {
        int f4 = t + p * 256;          // 0..2047 float4s of W (128x64 fp32)
        int k  = f4 >> 4;              // row of W
        int o  = (f4 & 15) * 4;        // col of W
        float4 v = reinterpret_cast<const float4*>(W)[f4];
        WT[o + 0][k] = (_Float16)v.x;
        WT[o + 1][k] = (_Float16)v.y;
        WT[o + 2][k] = (_Float16)v.z;
        WT[o + 3][k] = (_Float16)v.w;
    }
    __syncthreads();

    const int lane = t & 63;
    const int wv   = t >> 6;
    const int m16  = lane & 15;
    const int quad = lane >> 4;
    const int r0   = bx * 64 + wv * 16;
    int ra = r0 + m16; if (ra >= n) ra = n - 1;

    const float4* xrow = reinterpret_cast<const float4*>(X + (size_t)ra * 128);
    half8v a[4];
#pragma unroll
    for (int h = 0; h < 4; ++h) {
        int f0 = (h * 32 + quad * 8) >> 2;
        float4 v0 = xrow[f0];
        float4 v1 = xrow[f0 + 1];
        a[h][0] = (_Float16)v0.x; a[h][1] = (_Float16)v0.y;
        a[h][2] = (_Float16)v0.z; a[h][3] = (_Float16)v0.w;
        a[h][4] = (_Float16)v1.x; a[h][5] = (_Float16)v1.y;
        a[h][6] = (_Float16)v1.z; a[h][7] = (_Float16)v1.w;
    }
#pragma unroll
    for (int tt = 0; tt < 4; ++tt) {
        const half8v* wt = reinterpret_cast<const half8v*>(&WT[tt * 16 + m16][0]);
        float4v z = {0.f, 0.f, 0.f, 0.f};
#pragma unroll
        for (int h = 0; h < 4; ++h)
            z = __builtin_amdgcn_mfma_f32_16x16x32_f16(a[h], wt[h * 4 + quad], z, 0, 0, 0);
#pragma unroll
        for (int reg = 0; reg < 4; ++reg) {
            int row = r0 + quad * 4 + reg;
            if (row < n)
                Aout[(size_t)row * 64 + tt * 16 + m16] = __float2half_rn(z[reg]);
        }
    }
}

// ---- pack scatter: one hist chunk per block; digit bases from local scan --
__device__ __forceinline__ void pack_body(const int* __restrict__ ei,
                                          const int* __restrict__ histM,
                                          const int* __restrict__ totals,
                                          int* __restrict__ packed,
                                          int E, int ND, int b) {
    __shared__ int pairs[256];
    __shared__ int cbs[MAXD];
    __shared__ int cur[MAXD];
    const int tid = threadIdx.x;
    digit_base_scan(totals, ND, pairs, cbs);
    for (int t = tid; t < ND; t += 256)
        cur[t] = cbs[t] + histM[(size_t)b * MAXD + t];
    __syncthreads();
    const int base = b * EB;
    for (int it = 0; it < EB / 256; it += 4) {
        int s[4], d[4]; bool ok[4];
#pragma unroll
        for (int u = 0; u < 4; ++u) {
            int e = base + (it + u) * 256 + tid;
            ok[u] = e < E;
            if (ok[u]) { s[u] = ei[e]; d[u] = ei[E + e]; }
        }
#pragma unroll
        for (int u = 0; u < 4; ++u) {
            if (ok[u]) {
                int pos = atomicAdd(&cur[d[u] >> 8], 1);
                packed[pos] = (s[u] << 8) | (d[u] & 255);
            }
        }
    }
}

// Fused: hist + first slice of layer-1 GEMM.
__global__ __launch_bounds__(256) void hist_gemm1_k(
    const int* __restrict__ ei, int* __restrict__ histM, int E,
    const float* __restrict__ x, const float* __restrict__ W1,
    __half* __restrict__ A1, int n, int NH) {
    const int bx = blockIdx.x;
    if (bx < NH) hist_body(ei, histM, E, bx);
    else         gemm1_mfma_body(x, W1, A1, n, bx - NH);
}

// Fused: pack + remaining layer-1 GEMM blocks.
__global__ __launch_bounds__(256) void pack_gemm1_k(
    const int* __restrict__ ei, const int* __restrict__ histM,
    const int* __restrict__ totals, int* __restrict__ packed,
    const float* __restrict__ x, const float* __restrict__ W1,
    __half* __restrict__ A1, int n, int E, int ND, int NPB, int G1) {
    const int bx = blockIdx.x;
    if (bx < NPB) pack_body(ei, histM, totals, packed, E, ND, bx);
    else          gemm1_mfma_body(x, W1, A1, n, G1 + bx - NPB);
}

// ---- per-coarse-bucket finalize (padded x8 CSR, rpc int4, A1 scale) -------
__global__ __launch_bounds__(256) void bucket_k(const int* __restrict__ packed,
                                                const int* __restrict__ totals,
                                                int ND,
                                                int* __restrict__ col,
                                                int4* __restrict__ rpc,
                                                float* __restrict__ dinv,
                                                const __half* __restrict__ Araw,
                                                __half* __restrict__ Th, int n) {
    __shared__ int   pairs[256];
    __shared__ int   cbs[MAXD];
    __shared__ int   hist[256];
    __shared__ int   pref[256];
    __shared__ int   cur[256];
    __shared__ float dinv_l[256];

    const int tid = threadIdx.x;
    const int dg  = blockIdx.x;
    digit_base_scan(totals, ND, pairs, cbs);
    const int base  = cbs[dg];
    const int m     = totals[dg];
    const int basep = base + dg * PADSLACK;

    hist[tid] = 0;
    __syncthreads();
    for (int k0 = 0; k0 < m; k0 += 1024) {
        int v[4]; bool ok[4];
#pragma unroll
        for (int u = 0; u < 4; ++u) {
            int k = k0 + u * 256 + tid;
            ok[u] = k < m;
            v[u] = ok[u] ? packed[base + k] : 0;
        }
#pragma unroll
        for (int u = 0; u < 4; ++u)
            if (ok[u]) atomicAdd(&hist[v[u] & 255], 1);
    }
    __syncthreads();
    const int deg   = hist[tid];
    const int cnt_p = (deg + 8) & ~7;  // >= deg+1, multiple of 8
    pref[tid] = cnt_p;
    __syncthreads();
    for (int off = 1; off < 256; off <<= 1) {
        int x = (tid >= off) ? pref[tid - off] : 0;
        __syncthreads();
        pref[tid] += x;
        __syncthreads();
    }
    const int rp = basep + pref[tid] - cnt_p;
    const float di = rsqrtf((float)(deg + 1));
    dinv_l[tid] = di;
    cur[tid] = rp + 1;
    const int d = dg * 256 + tid;
    if (d < n) {
        rpc[d]  = make_int4(rp, cnt_p, __float_as_int(di), 0);
        dinv[d] = di;
        col[rp] = d;                                            // self slot
        for (int k = deg + 1; k < cnt_p; ++k) col[rp + k] = n;  // sentinel pads
    }
    __syncthreads();
    for (int k0 = 0; k0 < m; k0 += 1024) {
        int v[4]; bool ok[4];
#pragma unroll
        for (int u = 0; u < 4; ++u) {
            int k = k0 + u * 256 + tid;
            ok[u] = k < m;
            v[u] = ok[u] ? packed[base + k] : 0;
        }
#pragma unroll
        for (int u = 0; u < 4; ++u) {
            if (ok[u]) {
                int pos = atomicAdd(&cur[v[u] & 255], 1);
                col[pos] = v[u] >> 8;
            }
        }
    }
    // ---- scale fp16 staging by dinv -> fp16 table (fp32 math in between) --
    const int r0 = dg * 256;
#pragma unroll 4
    for (int it = 0; it < 16; ++it) {
        int idx = it * 256 + tid;
        int rl  = idx >> 4;
        int r   = r0 + rl;
        if (r < n) {
            union { uint2 u; __half h[4]; } iv;
            iv.u = reinterpret_cast<const uint2*>(Araw)[(size_t)r * 16 + (idx & 15)];
            float dd = dinv_l[rl];
            union { ushort4 u; __half h[4]; } pk;
            pk.h[0] = __float2half_rn(__half2float(iv.h[0]) * dd);
            pk.h[1] = __float2half_rn(__half2float(iv.h[1]) * dd);
            pk.h[2] = __float2half_rn(__half2float(iv.h[2]) * dd);
            pk.h[3] = __float2half_rn(__half2float(iv.h[3]) * dd);
            reinterpret_cast<ushort4*>(Th)[(size_t)r * 16 + (idx & 15)] = pk.u;
        }
    }
    if (dg == 0 && tid < 16) {
        uint2 z; z.x = 0u; z.y = 0u;
        reinterpret_cast<uint2*>(Th)[(size_t)n * 16 + tid] = z;
    }
}

// ---- straight-line batch: NB groups of 8 edges, all gathers unconditional -
// Table row stride in uint2 units == LR (16 -> 128B rows, 8 -> dense 64B).
template <int NB, int LR>
__device__ __forceinline__ void gather_batch(int c_l, const uint2* __restrict__ T2,
                                             int q, int sw, float4& acc) {
    constexpr int NSW = 64 / LR;
    constexpr int GPE = 8 / NSW;
    constexpr int NV  = NB * GPE;
    const half2v s10 = {(_Float16)1.f, (_Float16)0.f};
    const half2v s01 = {(_Float16)0.f, (_Float16)1.f};
    uint2 v[NV];
#pragma unroll
    for (int g = 0; g < NB; ++g)
#pragma unroll
        for (int u = 0; u < GPE; ++u) {
            int cc = __shfl(c_l, g * 8 + u * NSW + sw, 64);
            v[g * GPE + u] = T2[(size_t)cc * LR + q];
        }
#pragma unroll
    for (int k = 0; k < NV; ++k) {
        union { uint2 uu; half2v h[2]; } cv; cv.uu = v[k];
        acc.x = fdot2f(cv.h[0], s10, acc.x);
        acc.y = fdot2f(cv.h[0], s01, acc.y);
        acc.z = fdot2f(cv.h[1], s10, acc.z);
        acc.w = fdot2f(cv.h[1], s01, acc.w);
    }
}

// ---- gather one node (LR=16 path): switch + rare fallback -----------------
__device__ __forceinline__ void gather_node16(const int4& rc_a, int c_a,
                                              const uint2* __restrict__ T2,
                                              const int* __restrict__ col,
                                              int lane, int q, int sw,
                                              float4& acc) {
    const int cnt   = rc_a.y;
    const int start = rc_a.x;
    if (cnt <= 64) {
        switch (cnt >> 3) {            // 1..8 groups of 8
            case 1: gather_batch<1, 16>(c_a, T2, q, sw, acc); break;
            case 2: gather_batch<2, 16>(c_a, T2, q, sw, acc); break;
            case 3: gather_batch<3, 16>(c_a, T2, q, sw, acc); break;
            case 4: gather_batch<4, 16>(c_a, T2, q, sw, acc); break;
            case 5: gather_batch<5, 16>(c_a, T2, q, sw, acc); break;
            case 6: gather_batch<6, 16>(c_a, T2, q, sw, acc); break;
            case 7: gather_batch<7, 16>(c_a, T2, q, sw, acc); break;
            default: gather_batch<8, 16>(c_a, T2, q, sw, acc); break;
        }
    } else {
        const half2v s10 = {(_Float16)1.f, (_Float16)0.f};
        const half2v s01 = {(_Float16)0.f, (_Float16)1.f};
        for (int base = 0; base < cnt; base += 64) {
            const int m = min(64, cnt - base);   // multiple of 8
            int c_l = col[start + base + lane];
            for (int jg = 0; jg < m; jg += 8) {
                int cc[2]; uint2 v[2];
#pragma unroll
                for (int u = 0; u < 2; ++u)
                    cc[u] = __shfl(c_l, jg + u * 4 + sw, 64);
#pragma unroll
                for (int u = 0; u < 2; ++u) v[u] = T2[(size_t)cc[u] * 16 + q];
#pragma unroll
                for (int u = 0; u < 2; ++u) {
                    union { uint2 uu; half2v h[2]; } cv; cv.uu = v[u];
                    acc.x = fdot2f(cv.h[0], s10, acc.x);
                    acc.y = fdot2f(cv.h[0], s01, acc.y);
                    acc.z = fdot2f(cv.h[1], s10, acc.z);
                    acc.w = fdot2f(cv.h[1], s01, acc.w);
                }
            }
        }
    }
}

// ---- R21: fused agg + next-layer MFMA GEMM --------------------------------
// Chunked: wave w owns nodes [w*16, w*16+16).  Gather phase identical per
// node (R13 pipeline, now contiguous rpc/col); h rows staged in per-wave LDS
// (stride 72 fp16: 16B-aligned b128 reads, 2-way banks); then NT x 2 MFMAs
// (same fragment path as the proven gemm_mfma_k), x dinv, write next table.
template <int OUT, int TSTRIDE>   // 64,64 (layers 2,3) | 32,32 (layer 4 dense)
__global__ __launch_bounds__(256, 6) void aggemm_k(
    const __half* __restrict__ Tin, const int4* __restrict__ rpc,
    const int* __restrict__ col, const float* __restrict__ bias,
    const float* __restrict__ W, __half* __restrict__ Tout, int n) {
    constexpr int NT = OUT / 16;
    __shared__ _Float16 hrows[4][16 * 72];
    __shared__ float    dinvb[4][16];

    // zero output sentinel row (row n); idempotent, read only next dispatch
    if (blockIdx.x == 0 && threadIdx.x < TSTRIDE / 4)
        reinterpret_cast<uint2*>(Tout)[(size_t)n * (TSTRIDE / 4) + threadIdx.x] =
            make_uint2(0u, 0u);

    const int lane = threadIdx.x & 63;
    const int wv   = threadIdx.x >> 6;
    const int q    = lane & 15;     // LR=16
    const int sw   = lane >> 4;
    const int m16  = q;
    const int quad = sw;
    const int wid  = (blockIdx.x * blockDim.x + threadIdx.x) >> 6;
    const int base = wid * 16;
    if (base >= n) return;

    const uint2* __restrict__ T2 = reinterpret_cast<const uint2*>(Tin);
    const float4 b4 = reinterpret_cast<const float4*>(bias)[q];

    // B-fragments for next-layer GEMM (same layout as gemm_mfma_k)
    half8v bfrag[NT][2];
#pragma unroll
    for (int t = 0; t < NT; ++t)
#pragma unroll
        for (int h = 0; h < 2; ++h)
#pragma unroll
            for (int j = 0; j < 8; ++j)
                bfrag[t][h][j] = (_Float16)W[(size_t)(h * 32 + quad * 8 + j) * OUT
                                             + t * 16 + m16];

    // ---- gather phase: 16 nodes, R13 dist-2/1 pipeline --------------------
    int i1 = base + 1; if (i1 >= n) i1 = n - 1;
    int4 rc_a = rpc[base];
    int4 rc_b = rpc[i1];
    int  c_a  = col[rc_a.x + lane];   // slack-safe

#pragma unroll 2
    for (int kb = 0; kb < 16; ++kb) {
        int ic = base + kb + 2; if (ic >= n) ic = n - 1;
        int4 rc_c = rpc[ic];
        int  c_nx = col[rc_b.x + lane];

        const float di = __int_as_float(rc_a.z);
        float4 acc = make_float4(0.f, 0.f, 0.f, 0.f);
        gather_node16(rc_a, c_a, T2, col, lane, q, sw, acc);
#pragma unroll
        for (int off = 16; off < 64; off <<= 1) {
            acc.x += __shfl_xor(acc.x, off, 64);
            acc.y += __shfl_xor(acc.y, off, 64);
            acc.z += __shfl_xor(acc.z, off, 64);
            acc.w += __shfl_xor(acc.w, off, 64);
        }
        float4 h;
        h.x = fmaxf(fmaf(di, acc.x, b4.x), 0.f);
        h.y = fmaxf(fmaf(di, acc.y, b4.y), 0.f);
        h.z = fmaxf(fmaf(di, acc.z, b4.z), 0.f);
        h.w = fmaxf(fmaf(di, acc.w, b4.w), 0.f);
        if (sw == 0) {
            union { ushort4 u; __half hh[4]; } pk;
            pk.hh[0] = __float2half_rn(h.x);
            pk.hh[1] = __float2half_rn(h.y);
            pk.hh[2] = __float2half_rn(h.z);
            pk.hh[3] = __float2half_rn(h.w);
            *reinterpret_cast<ushort4*>(&hrows[wv][kb * 72 + 4 * q]) = pk.u;
        }
        if (lane == 0) dinvb[wv][kb] = di;
        rc_a = rc_b; rc_b = rc_c; c_a = c_nx;
    }

    // ---- gemm phase (wave-local LDS; in-order lgkm waits, no barrier) -----
    const _Float16* hl = &hrows[wv][0];
    half8v a0 = *reinterpret_cast<const half8v*>(&hl[m16 * 72 + quad * 8]);
    half8v a1 = *reinterpret_cast<const half8v*>(&hl[m16 * 72 + 32 + quad * 8]);
#pragma unroll
    for (int t = 0; t < NT; ++t) {
        float4v z = {0.f, 0.f, 0.f, 0.f};
        z = __builtin_amdgcn_mfma_f32_16x16x32_f16(a0, bfrag[t][0], z, 0, 0, 0);
        z = __builtin_amdgcn_mfma_f32_16x16x32_f16(a1, bfrag[t][1], z, 0, 0, 0);
#pragma unroll
        for (int reg = 0; reg < 4; ++reg) {
            int row = base + quad * 4 + reg;
            if (row < n) {
                float di2 = dinvb[wv][quad * 4 + reg];
                Tout[(size_t)row * TSTRIDE + t * 16 + m16] =
                    (_Float16)(z[reg] * di2);
            }
        }
    }
}

// ---- final agg (LR=8, dense 32ch table, fused head) -----------------------
template <int LR, bool FUSE_HEAD>
__global__ __launch_bounds__(256, 8) void agg_k(const __half* __restrict__ T,
                                             const int4* __restrict__ rpc,
                                             const int* __restrict__ col,
                                             const float* __restrict__ bias,
                                             void* __restrict__ O, int n,
                                             const float* __restrict__ Wh,
                                             const float* __restrict__ bh) {
    constexpr int NSW = 64 / LR;     // 4 / 8
    constexpr int GPE = 8 / NSW;     // 2 / 1
    const int lane = threadIdx.x & 63;
    const int q    = lane % LR;
    const int sw   = lane / LR;
    const int wid  = (blockIdx.x * blockDim.x + threadIdx.x) >> 6;
    const int nw   = (gridDim.x * blockDim.x) >> 6;
    if (wid >= n) return;

    const uint2* __restrict__ T2 = reinterpret_cast<const uint2*>(T);
    const float4 b4 = reinterpret_cast<const float4*>(bias)[q];

    float wh[12]; float bh0 = 0.f, bh1 = 0.f, bh2 = 0.f;
    if constexpr (FUSE_HEAD) {
#pragma unroll
        for (int j = 0; j < 12; ++j) wh[j] = Wh[4 * q * 3 + j];
        bh0 = bh[0]; bh1 = bh[1]; bh2 = bh[2];
    }

    int ib = wid + nw; if (ib >= n) ib = n - 1;
    int4 rc_a = rpc[wid];
    int4 rc_b = rpc[ib];
    int  c_a  = col[rc_a.x + lane];

    for (int i = wid; i < n; i += nw) {
        int ic = i + 2 * nw; if (ic >= n) ic = n - 1;
        int4 rc_c = rpc[ic];
        int  c_nx = col[rc_b.x + lane];

        const int   cnt   = rc_a.y;
        const int   start = rc_a.x;
        const float di    = __int_as_float(rc_a.z);

        float4 acc = make_float4(0.f, 0.f, 0.f, 0.f);
        if (cnt <= 64) {
            switch (cnt >> 3) {
                case 1: gather_batch<1, LR>(c_a, T2, q, sw, acc); break;
                case 2: gather_batch<2, LR>(c_a, T2, q, sw, acc); break;
                case 3: gather_batch<3, LR>(c_a, T2, q, sw, acc); break;
                case 4: gather_batch<4, LR>(c_a, T2, q, sw, acc); break;
                case 5: gather_batch<5, LR>(c_a, T2, q, sw, acc); break;
                case 6: gather_batch<6, LR>(c_a, T2, q, sw, acc); break;
                case 7: gather_batch<7, LR>(c_a, T2, q, sw, acc); break;
                default: gather_batch<8, LR>(c_a, T2, q, sw, acc); break;
            }
        } else {
            const half2v s10 = {(_Float16)1.f, (_Float16)0.f};
            const half2v s01 = {(_Float16)0.f, (_Float16)1.f};
            for (int base = 0; base < cnt; base += 64) {
                const int m = min(64, cnt - base);
                int c_l = col[start + base + lane];
                for (int jg = 0; jg < m; jg += 8) {
                    int cc[GPE]; uint2 v[GPE];
#pragma unroll
                    for (int u = 0; u < GPE; ++u)
                        cc[u] = __shfl(c_l, jg + u * NSW + sw, 64);
#pragma unroll
                    for (int u = 0; u < GPE; ++u) v[u] = T2[(size_t)cc[u] * LR + q];
#pragma unroll
                    for (int u = 0; u < GPE; ++u) {
                        union { uint2 uu; half2v h[2]; } cv; cv.uu = v[u];
                        acc.x = fdot2f(cv.h[0], s10, acc.x);
                        acc.y = fdot2f(cv.h[0], s01, acc.y);
                        acc.z = fdot2f(cv.h[1], s10, acc.z);
                        acc.w = fdot2f(cv.h[1], s01, acc.w);
                    }
                }
            }
        }
#pragma unroll
        for (int off = LR; off < 64; off <<= 1) {
            acc.x += __shfl_xor(acc.x, off, 64);
            acc.y += __shfl_xor(acc.y, off, 64);
            acc.z += __shfl_xor(acc.z, off, 64);
            acc.w += __shfl_xor(acc.w, off, 64);
        }
        float4 h;
        h.x = fmaxf(fmaf(di, acc.x, b4.x), 0.f);
        h.y = fmaxf(fmaf(di, acc.y, b4.y), 0.f);
        h.z = fmaxf(fmaf(di, acc.z, b4.z), 0.f);
        h.w = fmaxf(fmaf(di, acc.w, b4.w), 0.f);
        if constexpr (!FUSE_HEAD) {
            if (sw == 0) {
                union { ushort4 u; __half hh[4]; } pk;
                pk.hh[0] = __float2half_rn(h.x);
                pk.hh[1] = __float2half_rn(h.y);
                pk.hh[2] = __float2half_rn(h.z);
                pk.hh[3] = __float2half_rn(h.w);
                ushort* base_p = (ushort*)O + (size_t)i * 64;
                *reinterpret_cast<ushort4*>(base_p + 4 * q) = pk.u;
            }
        } else {
            float* Of = (float*)O;
            float p0 = h.x * wh[0];
            float p1 = h.x * wh[1];
            float p2 = h.x * wh[2];
            p0 = fmaf(h.y, wh[3], p0);
            p1 = fmaf(h.y, wh[4], p1);
            p2 = fmaf(h.y, wh[5], p2);
            p0 = fmaf(h.z, wh[6], p0);
            p1 = fmaf(h.z, wh[7], p1);
            p2 = fmaf(h.z, wh[8], p2);
            p0 = fmaf(h.w, wh[9], p0);
            p1 = fmaf(h.w, wh[10], p1);
            p2 = fmaf(h.w, wh[11], p2);
#pragma unroll
            for (int off = 1; off < LR; off <<= 1) {
                p0 += __shfl_xor(p0, off, 64);
                p1 += __shfl_xor(p1, off, 64);
                p2 += __shfl_xor(p2, off, 64);
            }
            if (lane == 0) {
                Of[(size_t)i * 3 + 0] = p0 + bh0;
                Of[(size_t)i * 3 + 1] = p1 + bh1;
                Of[(size_t)i * 3 + 2] = p2 + bh2;
            }
        }
        rc_a = rc_b; rc_b = rc_c; c_a = c_nx;
    }
}

extern "C" void kernel_launch(void* const* d_in, const int* in_sizes, int n_in,
                              void* d_out, int out_size, void* d_ws, size_t ws_size,
                              hipStream_t stream) {
    const float* x  = (const float*)d_in[0];
    const int*   ei = (const int*)d_in[1];
    const float* W1 = (const float*)d_in[2];
    const float* b1 = (const float*)d_in[3];
    const float* W2 = (const float*)d_in[4];
    const float* b2 = (const float*)d_in[5];
    const float* W3 = (const float*)d_in[6];
    const float* b3 = (const float*)d_in[7];
    const float* W4 = (const float*)d_in[8];
    const float* b4 = (const float*)d_in[9];
    const float* Wh = (const float*)d_in[10];
    const float* bh = (const float*)d_in[11];
    float* out = (float*)d_out;

    const int n = in_sizes[0] / 128;
    const int E = in_sizes[1] / 2;
    const int ND   = (n + 255) / 256;    // coarse digits (<= MAXD)
    const int NBLK = (E + EB - 1) / EB;  // hist/pack blocks (<= 256)

    char* ws = (char*)d_ws;
    auto alloc = [&](size_t bytes) {
        char* p = ws;
        ws += (bytes + 255) & ~(size_t)255;
        return p;
    };
    int*    histM  = (int*)alloc((size_t)NBLK * MAXD * 4);
    int*    totals = (int*)alloc((size_t)MAXD * 4);
    int*    packed = (int*)alloc((size_t)E * 4);
    int*    col    = (int*)alloc(((size_t)E + (size_t)ND * PADSLACK + 256) * 4);
    int4*   rpc    = (int4*)alloc((size_t)n * 16);
    float*  dinv   = (float*)alloc((size_t)n * 4);
    __half* bufA   = (__half*)alloc((size_t)n * 64 * 2);        // gemm1 staging
    __half* T1     = (__half*)alloc(((size_t)n + 1) * 64 * 2);  // table ping
    __half* T2     = (__half*)alloc(((size_t)n + 1) * 64 * 2);  // table pong

    dim3 blk(256);
    const int G  = (n + 63) / 64;   // layer-1 gemm blocks
    const int G1 = G / 3;           // slice fused with hist
    const int G2 = G - G1;          // slice fused with pack
    const int agg_blocks = 2048;    // final agg: persistent, 8 WG/CU
    const int agm_blocks = (n + 16 * 4 - 1) / (16 * 4);  // 16 nodes/wave

    // ---- atomic-free CSR build + layer-1 transform ----
    hist_gemm1_k<<<dim3(NBLK + G1), blk, 0, stream>>>(ei, histM, E, x, W1, bufA, n, NBLK);
    scan_digits_k<<<dim3(ND), blk, 0, stream>>>(histM, totals, NBLK);
    pack_gemm1_k<<<dim3(NBLK + G2), blk, 0, stream>>>(ei, histM, totals, packed,
                                                      x, W1, bufA, n, E, ND, NBLK, G1);
    bucket_k<<<dim3(ND), blk, 0, stream>>>(packed, totals, ND, col, rpc,
                                           dinv, bufA, T1, n);
    // ---- fused agg+GEMM chain: T1 -> T2 -> T1 -> T2(dense 32ch) ----
    aggemm_k<64, 64><<<dim3(agm_blocks), blk, 0, stream>>>(T1, rpc, col, b1, W2, T2, n);
    aggemm_k<64, 64><<<dim3(agm_blocks), blk, 0, stream>>>(T2, rpc, col, b2, W3, T1, n);
    aggemm_k<32, 32><<<dim3(agm_blocks), blk, 0, stream>>>(T1, rpc, col, b3, W4, T2, n);
    // ---- final agg + head ----
    agg_k<8, true><<<dim3(agg_blocks), blk, 0, stream>>>(
        T2, rpc, col, b4, out, n, Wh, bh);
}